// Round 9
// baseline (1721.538 us; speedup 1.0000x reference)
//
#include <hip/hip_runtime.h>
#include <cstdint>
#include <cmath>

// Transformer encoder: B=256, L=100, D=512, F=2048, NL=4, H=8, hd=64.
// qkv/ffn1: 256x256 8-phase gemm256. fc/ffn2: gemm_ln (fused bias+res+LN),
// BM=128 x BN=512 x BK=32, 8 waves; round-9: fixed LDS swizzle (2-way max)
// + coalesced bf16 output via LDS round-trip.

#define NLAYERS 4
#define BB 256
#define LL 100
#define DD 512
#define FF 2048
#define NH 8
#define HD 64
#define MM (BB*LL)   // 25600 rows
#define ATT_R 112
#define ATT_K 128

typedef __bf16 bf16;
typedef bf16 bf16x8 __attribute__((ext_vector_type(8)));
typedef bf16 bf16x4 __attribute__((ext_vector_type(4)));
typedef float f32x4 __attribute__((ext_vector_type(4)));

__device__ __forceinline__ void load16(const void* g, void* l) {
  __builtin_amdgcn_global_load_lds(
      (const __attribute__((address_space(1))) void*)g,
      (__attribute__((address_space(3))) void*)l, 16, 0, 0);
}

// ---------------- positional encoding table [L][D] ----------------
__global__ void pe_kernel(float* __restrict__ pe) {
  const int idx = blockIdx.x * 256 + threadIdx.x;
  if (idx >= LL * DD) return;
  const int l = idx >> 9, d = idx & 511;
  const int i = d >> 1;
  const float div = expf((float)(2 * i) * (-9.210340371976184f / 512.f));
  const float ang = (float)l * div;
  pe[idx] = (d & 1) ? cosf(ang) : sinf(ang);
}

// ---------------- xb = bf16(2*x + pe) ----------------
__global__ __launch_bounds__(256) void x0_kernel(
    const float* __restrict__ xin, const float* __restrict__ pe,
    bf16* __restrict__ XB) {
  const size_t f = (size_t)blockIdx.x * 256 + threadIdx.x;
  const size_t e = f << 2;
  const int col  = (int)(e & 511);
  const int prow = (int)((e >> 9) % LL);
  const float4 xv = *(const float4*)(xin + e);
  const float4 pv = *(const float4*)(pe + (size_t)prow * DD + col);
  bf16x4 pk;
  pk[0] = (bf16)(2.f * xv.x + pv.x);
  pk[1] = (bf16)(2.f * xv.y + pv.y);
  pk[2] = (bf16)(2.f * xv.z + pv.z);
  pk[3] = (bf16)(2.f * xv.w + pv.w);
  *(bf16x4*)(XB + e) = pk;
}

// ---------------- weight cast + transpose: [K][N] f32 -> [N][K] bf16 ----------------
__global__ void transpose_cast(const float* __restrict__ src, bf16* __restrict__ dst,
                               int K, int N) {
  __shared__ float tile[32][33];
  const int z = blockIdx.z;
  src += (size_t)z * K * N;
  dst += (size_t)z * K * N;
  const int k0 = blockIdx.y * 32, n0 = blockIdx.x * 32;
  const int tx = threadIdx.x, ty = threadIdx.y;
  #pragma unroll
  for (int i = 0; i < 32; i += 8)
    tile[ty + i][tx] = src[(size_t)(k0 + ty + i) * N + n0 + tx];
  __syncthreads();
  #pragma unroll
  for (int i = 0; i < 32; i += 8)
    dst[(size_t)(n0 + ty + i) * K + k0 + tx] = (bf16)tile[tx][ty + i];
}

// ============ 256x256 8-phase GEMM (round-4 verified) ============
__device__ __forceinline__ void stage_chunk(const bf16* __restrict__ src, int ldk,
                                            int grow0, int kt, bf16* chunk,
                                            int tid, int w) {
  const int rr = tid >> 3;
  const int cb = (tid & 7) ^ (rr & 7);
  const bf16* g = src + (size_t)(grow0 + rr) * ldk + (kt << 6) + (cb << 3);
  load16(g, chunk + (w << 9));
  load16(g + ((size_t)ldk << 6), chunk + 4096 + (w << 9));
}

__device__ __forceinline__ bf16x8 lds_frag(const bf16* chunk, int lrow, int cb) {
  return *(const bf16x8*)(chunk + (lrow << 6) + ((cb ^ (lrow & 7)) << 3));
}

template<int OUT_BF16, int RELU>
__global__ __launch_bounds__(512) void gemm256(
    const bf16* __restrict__ A, const bf16* __restrict__ Bt,
    const float* __restrict__ bias, void* __restrict__ Cv,
    int N, int K) {
  __shared__ __align__(16) bf16 sA[2][2][128 * 64];
  __shared__ __align__(16) bf16 sB[2][2][128 * 64];
  const int tid = threadIdx.x;
  const int w = tid >> 6, lane = tid & 63;
  const int wr = w >> 2, wc = w & 3;
  const int lr16 = lane & 15, lg = lane >> 4;
  const int NT = K >> 6;

  const int nwg = gridDim.x * gridDim.y;
  const int orig = blockIdx.y * gridDim.x + blockIdx.x;
  const int q = nwg >> 3, r = nwg & 7;
  const int xcd = orig & 7, lo = orig >> 3;
  const int swz = (xcd < r ? xcd * (q + 1) : r * (q + 1) + (xcd - r) * q) + lo;
  const int bn = (swz % gridDim.x) << 8;
  const int bm = (swz / gridDim.x) << 8;

  f32x4 acc[8][4] = {};
  bf16x8 Av[4][2], Bv0[2][2], Bv1[2][2];

  stage_chunk(A,  K, bm,       0, sA[0][0], tid, w);
  stage_chunk(Bt, K, bn,       0, sB[0][0], tid, w);
  stage_chunk(A,  K, bm + 128, 0, sA[0][1], tid, w);
  stage_chunk(Bt, K, bn + 128, 0, sB[0][1], tid, w);
  stage_chunk(A,  K, bm,       1, sA[1][0], tid, w);
  stage_chunk(Bt, K, bn,       1, sB[1][0], tid, w);

  for (int t = 0; t < NT; ++t) {
    const int b = t & 1;
    if (t < NT - 1) asm volatile("s_waitcnt vmcnt(4)" ::: "memory");
    else            asm volatile("s_waitcnt vmcnt(0)" ::: "memory");
    __builtin_amdgcn_s_barrier();

    #pragma unroll
    for (int m = 0; m < 4; ++m) {
      const int lrow = m * 32 + wr * 16 + lr16;
      Av[m][0] = lds_frag(sA[b][0], lrow, lg);
      Av[m][1] = lds_frag(sA[b][0], lrow, 4 + lg);
    }
    #pragma unroll
    for (int n = 0; n < 2; ++n) {
      const int lrow = n * 64 + wc * 16 + lr16;
      Bv0[n][0] = lds_frag(sB[b][0], lrow, lg);
      Bv0[n][1] = lds_frag(sB[b][0], lrow, 4 + lg);
    }
    if (t + 1 < NT) stage_chunk(A, K, bm + 128, t + 1, sA[b ^ 1][1], tid, w);
    __builtin_amdgcn_s_barrier();
    __builtin_amdgcn_s_setprio(1);
    #pragma unroll
    for (int m = 0; m < 4; ++m)
      #pragma unroll
      for (int n = 0; n < 2; ++n) {
        acc[m][n] = __builtin_amdgcn_mfma_f32_16x16x32_bf16(Av[m][0], Bv0[n][0], acc[m][n], 0, 0, 0);
        acc[m][n] = __builtin_amdgcn_mfma_f32_16x16x32_bf16(Av[m][1], Bv0[n][1], acc[m][n], 0, 0, 0);
      }
    __builtin_amdgcn_s_setprio(0);
    __builtin_amdgcn_s_barrier();

    #pragma unroll
    for (int n = 0; n < 2; ++n) {
      const int lrow = n * 64 + wc * 16 + lr16;
      Bv1[n][0] = lds_frag(sB[b][1], lrow, lg);
      Bv1[n][1] = lds_frag(sB[b][1], lrow, 4 + lg);
    }
    if (t + 1 < NT) stage_chunk(Bt, K, bn + 128, t + 1, sB[b ^ 1][1], tid, w);
    __builtin_amdgcn_s_barrier();
    __builtin_amdgcn_s_setprio(1);
    #pragma unroll
    for (int m = 0; m < 4; ++m)
      #pragma unroll
      for (int n = 0; n < 2; ++n) {
        acc[m][n + 2] = __builtin_amdgcn_mfma_f32_16x16x32_bf16(Av[m][0], Bv1[n][0], acc[m][n + 2], 0, 0, 0);
        acc[m][n + 2] = __builtin_amdgcn_mfma_f32_16x16x32_bf16(Av[m][1], Bv1[n][1], acc[m][n + 2], 0, 0, 0);
      }
    __builtin_amdgcn_s_setprio(0);
    __builtin_amdgcn_s_barrier();

    #pragma unroll
    for (int m = 0; m < 4; ++m) {
      const int lrow = m * 32 + wr * 16 + lr16;
      Av[m][0] = lds_frag(sA[b][1], lrow, lg);
      Av[m][1] = lds_frag(sA[b][1], lrow, 4 + lg);
    }
    if (t + 2 < NT) stage_chunk(A, K, bm, t + 2, sA[b][0], tid, w);
    __builtin_amdgcn_s_barrier();
    __builtin_amdgcn_s_setprio(1);
    #pragma unroll
    for (int m = 0; m < 4; ++m)
      #pragma unroll
      for (int n = 0; n < 2; ++n) {
        acc[m + 4][n] = __builtin_amdgcn_mfma_f32_16x16x32_bf16(Av[m][0], Bv0[n][0], acc[m + 4][n], 0, 0, 0);
        acc[m + 4][n] = __builtin_amdgcn_mfma_f32_16x16x32_bf16(Av[m][1], Bv0[n][1], acc[m + 4][n], 0, 0, 0);
      }
    __builtin_amdgcn_s_setprio(0);
    __builtin_amdgcn_s_barrier();

    if (t + 2 < NT) stage_chunk(Bt, K, bn, t + 2, sB[b][0], tid, w);
    __builtin_amdgcn_s_barrier();
    __builtin_amdgcn_s_setprio(1);
    #pragma unroll
    for (int m = 0; m < 4; ++m)
      #pragma unroll
      for (int n = 0; n < 2; ++n) {
        acc[m + 4][n + 2] = __builtin_amdgcn_mfma_f32_16x16x32_bf16(Av[m][0], Bv1[n][0], acc[m + 4][n + 2], 0, 0, 0);
        acc[m + 4][n + 2] = __builtin_amdgcn_mfma_f32_16x16x32_bf16(Av[m][1], Bv1[n][1], acc[m + 4][n + 2], 0, 0, 0);
      }
    __builtin_amdgcn_s_setprio(0);
  }

  const int g4 = (lane >> 4) << 2;
  #pragma unroll
  for (int n = 0; n < 4; ++n) {
    const int col = bn + n * 64 + wc * 16 + lr16;
    const float bvv = bias ? bias[col] : 0.f;
    #pragma unroll
    for (int m = 0; m < 8; ++m) {
      const int row = bm + m * 32 + wr * 16 + g4;
      #pragma unroll
      for (int j = 0; j < 4; ++j) {
        float v = acc[m][n][j] + bvv;
        if (RELU) v = fmaxf(v, 0.f);
        if (OUT_BF16) ((bf16*)Cv)[(size_t)(row + j) * N + col] = (bf16)v;
        else          ((float*)Cv)[(size_t)(row + j) * N + col] = v;
      }
    }
  }
}

// ============ gemm_ln v2: fused GEMM + bias + residual + LayerNorm ============
// BM=128, BN=512(=N), BK=32, 8 waves (each 128x64 cols), LDS 80KB.
// Swizzle: slot s at row r holds col-block s^((r>>1)&3)  -> max 2-way (free).
// Epilogue: LN'd bf16 staged to LDS (pitch 520), read back row-major,
// written as coalesced 1024B/wave stores.
template<int WRITE_F32>
__global__ __launch_bounds__(512) void gemm_ln(
    const bf16* __restrict__ A, const bf16* __restrict__ Bt,
    const float* __restrict__ bias, const bf16* __restrict__ RES,
    const float* __restrict__ lng, const float* __restrict__ lnb,
    bf16* __restrict__ XB, float* __restrict__ XF, int K) {
  __shared__ __align__(16) bf16 sA[2][128 * 32];   // 16 KB
  __shared__ __align__(16) bf16 sB[2][512 * 32];   // 64 KB
  const int tid = threadIdx.x;
  const int w = tid >> 6, lane = tid & 63;
  const int wc = w;
  const int lr16 = lane & 15, lg = lane >> 4;
  const int NT = K >> 5;

  // XCD swizzle (200 blocks % 8 == 0)
  const int qq = gridDim.x >> 3;
  const int swz = (blockIdx.x & 7) * qq + (blockIdx.x >> 3);
  const int bm = swz << 7;

  // staging sources, pre-swizzled: granule p=(tid) -> row=tid>>2, slot=tid&3,
  // content col-block = slot ^ ((row>>1)&3)
  const int rr = tid >> 2;
  const int cbl = (tid & 3) ^ ((rr >> 1) & 3);
  const bf16* gA  = A  + (size_t)(bm + rr) * K + (cbl << 3);
  const bf16* gB0 = Bt + (size_t)(0   + rr) * K + (cbl << 3);
  const bf16* gB1 = Bt + (size_t)(128 + rr) * K + (cbl << 3);
  const bf16* gB2 = Bt + (size_t)(256 + rr) * K + (cbl << 3);
  const bf16* gB3 = Bt + (size_t)(384 + rr) * K + (cbl << 3);

  f32x4 acc[8][4] = {};
  bf16x8 Af[4], Bf[4];

  load16(gA,       sA[0] + (w << 9));
  load16(gB0,      sB[0] + 0 * 4096 + (w << 9));
  load16(gB1,      sB[0] + 1 * 4096 + (w << 9));
  load16(gB2,      sB[0] + 2 * 4096 + (w << 9));
  load16(gB3,      sB[0] + 3 * 4096 + (w << 9));
  load16(gB0 + 32, sB[1] + 0 * 4096 + (w << 9));
  load16(gB1 + 32, sB[1] + 1 * 4096 + (w << 9));
  load16(gB2 + 32, sB[1] + 2 * 4096 + (w << 9));
  load16(gB3 + 32, sB[1] + 3 * 4096 + (w << 9));

  for (int t = 0; t < NT; ++t) {
    const int pb = t & 1;
    const bf16* bufA = sA[pb];
    const bf16* bufB = sB[pb];
    if (t < NT - 1) asm volatile("s_waitcnt vmcnt(4)" ::: "memory");
    else            asm volatile("s_waitcnt vmcnt(0)" ::: "memory");
    __builtin_amdgcn_s_barrier();

    // ph0: read A m0-3 + all B frags; stage A(t+1); MFMA m0-3
    #pragma unroll
    for (int m = 0; m < 4; ++m) {
      const int row = m * 16 + lr16;
      Af[m] = *(const bf16x8*)&bufA[row * 32 + ((lg ^ ((row >> 1) & 3)) << 3)];
    }
    #pragma unroll
    for (int n = 0; n < 4; ++n) {
      const int row = wc * 64 + n * 16 + lr16;
      Bf[n] = *(const bf16x8*)&bufB[row * 32 + ((lg ^ ((row >> 1) & 3)) << 3)];
    }
    if (t + 1 < NT) load16(gA + (t + 1) * 32, sA[pb ^ 1] + (w << 9));
    __builtin_amdgcn_s_barrier();
    __builtin_amdgcn_s_setprio(1);
    #pragma unroll
    for (int m = 0; m < 4; ++m)
      #pragma unroll
      for (int n = 0; n < 4; ++n)
        acc[m][n] = __builtin_amdgcn_mfma_f32_16x16x32_bf16(Af[m], Bf[n], acc[m][n], 0, 0, 0);
    __builtin_amdgcn_s_setprio(0);
    __builtin_amdgcn_s_barrier();

    // ph1: read A m4-7; stage B(t+2); MFMA m4-7
    #pragma unroll
    for (int m = 0; m < 4; ++m) {
      const int row = (m + 4) * 16 + lr16;
      Af[m] = *(const bf16x8*)&bufA[row * 32 + ((lg ^ ((row >> 1) & 3)) << 3)];
    }
    if (t + 2 < NT) {
      const int ko = (t + 2) * 32;
      load16(gB0 + ko, sB[pb] + 0 * 4096 + (w << 9));
      load16(gB1 + ko, sB[pb] + 1 * 4096 + (w << 9));
      load16(gB2 + ko, sB[pb] + 2 * 4096 + (w << 9));
      load16(gB3 + ko, sB[pb] + 3 * 4096 + (w << 9));
    }
    __builtin_amdgcn_s_barrier();
    __builtin_amdgcn_s_setprio(1);
    #pragma unroll
    for (int m = 0; m < 4; ++m)
      #pragma unroll
      for (int n = 0; n < 4; ++n)
        acc[m + 4][n] = __builtin_amdgcn_mfma_f32_16x16x32_bf16(Af[m], Bf[n], acc[m + 4][n], 0, 0, 0);
    __builtin_amdgcn_s_setprio(0);
  }

  // ---- fused epilogue ----
  __syncthreads();
  float* redS = (float*)sA;                // [128][16] f32 = 8 KB  (sA[0])
  float* muS  = ((float*)sA) + 2048;       // 256 f32 (sA[1] region)

  int colv[4];
  #pragma unroll
  for (int n = 0; n < 4; ++n) colv[n] = wc * 64 + n * 16 + lr16;

  // z = acc + bias + residual (fp32)
  #pragma unroll
  for (int m = 0; m < 8; ++m) {
    #pragma unroll
    for (int j = 0; j < 4; ++j) {
      const int row = m * 16 + (lg << 2) + j;
      const size_t gr = (size_t)(bm + row) * DD;
      #pragma unroll
      for (int n = 0; n < 4; ++n)
        acc[m][n][j] += bias[colv[n]] + (float)RES[gr + colv[n]];
    }
  }
  // per-row sums -> cross-wave reduce
  #pragma unroll
  for (int m = 0; m < 8; ++m) {
    #pragma unroll
    for (int j = 0; j < 4; ++j) {
      float s  = acc[m][0][j] + acc[m][1][j] + acc[m][2][j] + acc[m][3][j];
      float s2 = acc[m][0][j] * acc[m][0][j] + acc[m][1][j] * acc[m][1][j]
               + acc[m][2][j] * acc[m][2][j] + acc[m][3][j] * acc[m][3][j];
      #pragma unroll
      for (int off = 1; off < 16; off <<= 1) {
        s  += __shfl_xor(s, off, 64);
        s2 += __shfl_xor(s2, off, 64);
      }
      if (lr16 == 0) {
        const int row = m * 16 + (lg << 2) + j;
        redS[row * 16 + wc * 2]     = s;
        redS[row * 16 + wc * 2 + 1] = s2;
      }
    }
  }
  __syncthreads();
  if (tid < 128) {
    float s = 0.f, s2 = 0.f;
    #pragma unroll
    for (int wv = 0; wv < 8; ++wv) {
      s  += redS[tid * 16 + wv * 2];
      s2 += redS[tid * 16 + wv * 2 + 1];
    }
    const float mu  = s * (1.f / 512.f);
    const float var = s2 * (1.f / 512.f) - mu * mu;
    muS[tid]       = mu;
    muS[128 + tid] = rsqrtf(var + 1e-5f);
  }
  __syncthreads();

  float gmv[4], btv[4];
  #pragma unroll
  for (int n = 0; n < 4; ++n) { gmv[n] = lng[colv[n]]; btv[n] = lnb[colv[n]]; }

  // 4 passes of 32 rows: LN -> LDS (pitch 520) -> coalesced global write
  bf16* outS = sB[0];
  #pragma unroll 1
  for (int h = 0; h < 4; ++h) {
    #pragma unroll
    for (int mm = 0; mm < 2; ++mm) {
      const int m = h * 2 + mm;
      #pragma unroll
      for (int j = 0; j < 4; ++j) {
        const int row = m * 16 + (lg << 2) + j;
        const int rl  = mm * 16 + (lg << 2) + j;
        const float mu  = muS[row];
        const float inv = muS[128 + row];
        #pragma unroll
        for (int n = 0; n < 4; ++n) {
          const float o = (acc[m][n][j] - mu) * inv * gmv[n] + btv[n];
          outS[rl * 520 + colv[n]] = (bf16)o;
          if (WRITE_F32) XF[(size_t)(bm + row) * DD + colv[n]] = o;
        }
      }
    }
    __syncthreads();
    #pragma unroll
    for (int i = 0; i < 4; ++i) {
      const int rl = i * 8 + w;
      const bf16x8 v = *(const bf16x8*)&outS[rl * 520 + lane * 8];
      *(bf16x8*)&XB[(size_t)(bm + h * 32 + rl) * DD + lane * 8] = v;
    }
    __syncthreads();
  }
}

// ---------------- MFMA attention: one block (4 waves) per (b,h) ----------------
__global__ __launch_bounds__(256) void attn_mfma(
    const bf16* __restrict__ qkv, const int* __restrict__ mask,
    bf16* __restrict__ aout) {
  __shared__ __align__(16) bf16 sQ[ATT_R * 64];
  __shared__ __align__(16) bf16 sK[ATT_R * 64];
  __shared__ __align__(16) bf16 sVt[64 * 136];
  __shared__ __align__(16) bf16 sP[ATT_R * ATT_K];
  __shared__ int sM[ATT_R];
  const int bh = blockIdx.x, b = bh >> 3, h = bh & 7;
  const int tid = threadIdx.x, w = tid >> 6, lane = tid & 63;
  const int lr = lane & 15;
  const int lk = (lane >> 4) << 3;
  const int g  = lane >> 4;

  for (int i = tid; i < ATT_R * 64 / 8; i += 256) { ((int4*)sQ)[i] = int4{0,0,0,0}; ((int4*)sK)[i] = int4{0,0,0,0}; }
  for (int i = tid; i < 64 * 136 / 8; i += 256) ((int4*)sVt)[i] = int4{0,0,0,0};
  for (int i = tid; i < ATT_R * ATT_K / 8; i += 256) ((int4*)sP)[i] = int4{0,0,0,0};
  __syncthreads();

  const bf16* base = qkv + (size_t)(b * LL) * (3 * DD) + h * HD;
  for (int c = tid; c < LL * 8; c += 256) {
    const int l = c >> 3, u = c & 7;
    const bf16x8 qv = *(const bf16x8*)(base + (size_t)l * (3 * DD) + u * 8);
    const bf16x8 kv = *(const bf16x8*)(base + (size_t)l * (3 * DD) + DD + u * 8);
    const bf16x8 vv = *(const bf16x8*)(base + (size_t)l * (3 * DD) + 2 * DD + u * 8);
    const int qb = (l * 128 + u * 16) ^ ((l & 7) << 4);
    *(bf16x8*)((char*)sQ + qb) = qv;
    *(bf16x8*)((char*)sK + qb) = kv;
    #pragma unroll
    for (int j = 0; j < 8; ++j) sVt[(u * 8 + j) * 136 + l] = vv[j];
  }
  if (tid < ATT_R) sM[tid] = (tid < LL) ? mask[b * LL + tid] : 0;
  __syncthreads();

  #pragma unroll
  for (int fi = 0; fi < 2; ++fi) {
    const int fm = w + fi * 4;
    if (fm >= 7) continue;
    const int ar = fm * 16 + lr;
    const int abase = ar * 128;
    const int aswz = (ar & 7) << 4;
    const bf16x8 a0 = *(const bf16x8*)((char*)sQ + ((abase + lk * 2) ^ aswz));
    const bf16x8 a1 = *(const bf16x8*)((char*)sQ + ((abase + 64 + lk * 2) ^ aswz));
    f32x4 s[7];
    #pragma unroll
    for (int fn = 0; fn < 7; ++fn) {
      const int br = fn * 16 + lr;
      const int bswz = (br & 7) << 4;
      const bf16x8 b0 = *(const bf16x8*)((char*)sK + ((br * 128 + lk * 2) ^ bswz));
      const bf16x8 b1 = *(const bf16x8*)((char*)sK + ((br * 128 + 64 + lk * 2) ^ bswz));
      f32x4 acc = {};
      acc = __builtin_amdgcn_mfma_f32_16x16x32_bf16(a0, b0, acc, 0, 0, 0);
      acc = __builtin_amdgcn_mfma_f32_16x16x32_bf16(a1, b1, acc, 0, 0, 0);
      s[fn] = acc;
    }
    #pragma unroll
    for (int fn = 0; fn < 7; ++fn) {
      if (sM[fn * 16 + lr] == 0) {
        s[fn][0] = -INFINITY; s[fn][1] = -INFINITY;
        s[fn][2] = -INFINITY; s[fn][3] = -INFINITY;
      }
    }
    float sm[4];
    #pragma unroll
    for (int j = 0; j < 4; ++j) {
      float m = s[0][j];
      #pragma unroll
      for (int fn = 1; fn < 7; ++fn) m = fmaxf(m, s[fn][j]);
      #pragma unroll
      for (int off = 1; off < 16; off <<= 1) m = fmaxf(m, __shfl_xor(m, off, 64));
      float t = 0.f;
      #pragma unroll
      for (int fn = 0; fn < 7; ++fn) { const float p = __expf(s[fn][j] - m); s[fn][j] = p; t += p; }
      #pragma unroll
      for (int off = 1; off < 16; off <<= 1) t += __shfl_xor(t, off, 64);
      sm[j] = 1.f / t;
    }
    #pragma unroll
    for (int fn = 0; fn < 7; ++fn) {
      const int k = fn * 16 + lr;
      #pragma unroll
      for (int j = 0; j < 4; ++j) {
        const int rr = fm * 16 + 4 * g + j;
        const int byte = (rr * 256 + k * 2) ^ ((rr & 7) << 4);
        *(bf16*)((char*)sP + byte) = (bf16)(s[fn][j] * sm[j]);
      }
    }
  }
  __syncthreads();

  bf16x8 bV[4];
  #pragma unroll
  for (int ks = 0; ks < 4; ++ks)
    bV[ks] = *(const bf16x8*)((char*)sVt + ((w * 16 + lr) * 272 + ks * 64 + lk * 2));
  #pragma unroll
  for (int fm = 0; fm < 7; ++fm) {
    f32x4 acc = {};
    const int ar = fm * 16 + lr;
    const int aswz = (ar & 7) << 4;
    #pragma unroll
    for (int ks = 0; ks < 4; ++ks) {
      const bf16x8 aP = *(const bf16x8*)((char*)sP + ((ar * 256 + ks * 64 + lk * 2) ^ aswz));
      acc = __builtin_amdgcn_mfma_f32_16x16x32_bf16(aP, bV[ks], acc, 0, 0, 0);
    }
    const int d = h * HD + w * 16 + lr;
    #pragma unroll
    for (int j = 0; j < 4; ++j) {
      const int qr = fm * 16 + 4 * g + j;
      if (qr < LL) aout[(size_t)(b * LL + qr) * DD + d] = (bf16)acc[j];
    }
  }
}

extern "C" void kernel_launch(void* const* d_in, const int* in_sizes, int n_in,
                              void* d_out, int out_size, void* d_ws, size_t ws_size,
                              hipStream_t stream) {
  const float* x_in   = (const float*)d_in[0];
  const int*   mask   = (const int*)d_in[1];
  const float* qkv_w  = (const float*)d_in[2];
  const float* fc_w   = (const float*)d_in[3];
  const float* fc_b   = (const float*)d_in[4];
  const float* ln1_g  = (const float*)d_in[5];
  const float* ln1_b  = (const float*)d_in[6];
  const float* ln2_g  = (const float*)d_in[7];
  const float* ln2_b  = (const float*)d_in[8];
  const float* ffn_w1 = (const float*)d_in[9];
  const float* ffn_b1 = (const float*)d_in[10];
  const float* ffn_w2 = (const float*)d_in[11];
  const float* ffn_b2 = (const float*)d_in[12];

  char* ws = (char*)d_ws;
  size_t off = 0;
  auto alloc = [&](size_t bytes) -> void* {
    off = (off + 255) & ~(size_t)255;
    void* p = ws + off;
    off += bytes;
    return p;
  };
  bf16*  XB   = (bf16*) alloc((size_t)MM * DD * 2);
  bf16*  BIGB = (bf16*) alloc((size_t)MM * FF * 2);
  float* PE   = (float*)alloc((size_t)LL * DD * 4);
  bf16*  WQKV = (bf16*) alloc((size_t)NLAYERS * DD * 3 * DD * 2);
  bf16*  WFC  = (bf16*) alloc((size_t)NLAYERS * DD * DD * 2);
  bf16*  W1T  = (bf16*) alloc((size_t)NLAYERS * DD * FF * 2);
  bf16*  W2T  = (bf16*) alloc((size_t)NLAYERS * FF * DD * 2);
  bf16*  AOUT = BIGB + (size_t)MM * (3 * DD);
  (void)ws_size; (void)in_sizes; (void)n_in; (void)out_size;

  pe_kernel<<<200, 256, 0, stream>>>(PE);
  transpose_cast<<<dim3(48, 16, NLAYERS), dim3(32, 8), 0, stream>>>(qkv_w,  WQKV, 512, 1536);
  transpose_cast<<<dim3(16, 16, NLAYERS), dim3(32, 8), 0, stream>>>(fc_w,   WFC,  512, 512);
  transpose_cast<<<dim3(64, 16, NLAYERS), dim3(32, 8), 0, stream>>>(ffn_w1, W1T,  512, 2048);
  transpose_cast<<<dim3(16, 64, NLAYERS), dim3(32, 8), 0, stream>>>(ffn_w2, W2T,  2048, 512);
  x0_kernel<<<12800, 256, 0, stream>>>(x_in, PE, XB);

  for (int i = 0; i < NLAYERS; ++i) {
    // qkv = x @ qkv_w -> bf16 [M,1536]
    gemm256<1, 0><<<dim3(6, 100), 512, 0, stream>>>(
        XB, WQKV + (size_t)i * DD * 3 * DD, nullptr, BIGB, 3 * DD, DD);
    attn_mfma<<<BB * NH, 256, 0, stream>>>(BIGB, mask, AOUT);
    // x = LN(attn_out @ fc_w + fc_b + x)
    gemm_ln<0><<<200, 512, 0, stream>>>(
        AOUT, WFC + (size_t)i * DD * DD, fc_b + i * DD, XB,
        ln1_g + i * DD, ln1_b + i * DD, XB, nullptr, DD);
    // h = relu(x @ w1 + b1) -> bf16 [M,2048]
    gemm256<1, 1><<<dim3(8, 100), 512, 0, stream>>>(
        XB, W1T + (size_t)i * DD * FF, ffn_b1 + i * FF, BIGB, FF, DD);
    // x = LN(h @ w2 + b2 + x); final layer also writes fp32 d_out
    if (i == NLAYERS - 1)
      gemm_ln<1><<<200, 512, 0, stream>>>(
          BIGB, W2T + (size_t)i * FF * DD, ffn_b2 + i * DD, XB,
          ln2_g + i * DD, ln2_b + i * DD, XB, (float*)d_out, FF);
    else
      gemm_ln<0><<<200, 512, 0, stream>>>(
          BIGB, W2T + (size_t)i * FF * DD, ffn_b2 + i * DD, XB,
          ln2_g + i * DD, ln2_b + i * DD, XB, nullptr, FF);
  }
}

// Round 10
// 1199.191 us; speedup vs baseline: 1.4356x; 1.4356x over previous
//
#include <hip/hip_runtime.h>
#include <cstdint>
#include <cmath>

// Transformer encoder: B=256, L=100, D=512, F=2048, NL=4, H=8, hd=64.
// Round-10: revert to round-4 champion structure (gemm256 + ln_kernel).
// New: gemm128 BK=64 (16-MFMA phases, 64KB LDS -> 2 blocks/CU) for fc/ffn2.

#define NLAYERS 4
#define BB 256
#define LL 100
#define DD 512
#define FF 2048
#define NH 8
#define HD 64
#define MM (BB*LL)   // 25600 rows
#define ATT_R 112
#define ATT_K 128

typedef __bf16 bf16;
typedef bf16 bf16x8 __attribute__((ext_vector_type(8)));
typedef bf16 bf16x4 __attribute__((ext_vector_type(4)));
typedef float f32x4 __attribute__((ext_vector_type(4)));

__device__ __forceinline__ void load16(const void* g, void* l) {
  __builtin_amdgcn_global_load_lds(
      (const __attribute__((address_space(1))) void*)g,
      (__attribute__((address_space(3))) void*)l, 16, 0, 0);
}

// ---------------- positional encoding table [L][D] ----------------
__global__ void pe_kernel(float* __restrict__ pe) {
  const int idx = blockIdx.x * 256 + threadIdx.x;
  if (idx >= LL * DD) return;
  const int l = idx >> 9, d = idx & 511;
  const int i = d >> 1;
  const float div = expf((float)(2 * i) * (-9.210340371976184f / 512.f));
  const float ang = (float)l * div;
  pe[idx] = (d & 1) ? cosf(ang) : sinf(ang);
}

// ---------------- xb = bf16(2*x + pe) ----------------
__global__ __launch_bounds__(256) void x0_kernel(
    const float* __restrict__ xin, const float* __restrict__ pe,
    bf16* __restrict__ XB) {
  const size_t f = (size_t)blockIdx.x * 256 + threadIdx.x;
  const size_t e = f << 2;
  const int col  = (int)(e & 511);
  const int prow = (int)((e >> 9) % LL);
  const float4 xv = *(const float4*)(xin + e);
  const float4 pv = *(const float4*)(pe + (size_t)prow * DD + col);
  bf16x4 pk;
  pk[0] = (bf16)(2.f * xv.x + pv.x);
  pk[1] = (bf16)(2.f * xv.y + pv.y);
  pk[2] = (bf16)(2.f * xv.z + pv.z);
  pk[3] = (bf16)(2.f * xv.w + pv.w);
  *(bf16x4*)(XB + e) = pk;
}

// ---------------- weight cast + transpose: [K][N] f32 -> [N][K] bf16 ----------------
__global__ void transpose_cast(const float* __restrict__ src, bf16* __restrict__ dst,
                               int K, int N) {
  __shared__ float tile[32][33];
  const int z = blockIdx.z;
  src += (size_t)z * K * N;
  dst += (size_t)z * K * N;
  const int k0 = blockIdx.y * 32, n0 = blockIdx.x * 32;
  const int tx = threadIdx.x, ty = threadIdx.y;
  #pragma unroll
  for (int i = 0; i < 32; i += 8)
    tile[ty + i][tx] = src[(size_t)(k0 + ty + i) * N + n0 + tx];
  __syncthreads();
  #pragma unroll
  for (int i = 0; i < 32; i += 8)
    dst[(size_t)(n0 + ty + i) * K + k0 + tx] = (bf16)tile[tx][ty + i];
}

// ============ shared GEMM helpers (row*128B, 8 slots, XOR r&7 swizzle) ============
__device__ __forceinline__ void stage_chunk(const bf16* __restrict__ src, int ldk,
                                            int grow0, int kt, bf16* chunk,
                                            int tid, int w) {
  const int rr = tid >> 3;
  const int cb = (tid & 7) ^ (rr & 7);
  const bf16* g = src + (size_t)(grow0 + rr) * ldk + (kt << 6) + (cb << 3);
  load16(g, chunk + (w << 9));
  load16(g + ((size_t)ldk << 6), chunk + 4096 + (w << 9));
}

__device__ __forceinline__ bf16x8 lds_frag(const bf16* chunk, int lrow, int cb) {
  return *(const bf16x8*)(chunk + (lrow << 6) + ((cb ^ (lrow & 7)) << 3));
}

// ============ 256x256 8-phase GEMM (round-4 verified) ============
template<int OUT_BF16, int RELU>
__global__ __launch_bounds__(512) void gemm256(
    const bf16* __restrict__ A, const bf16* __restrict__ Bt,
    const float* __restrict__ bias, void* __restrict__ Cv,
    int N, int K) {
  __shared__ __align__(16) bf16 sA[2][2][128 * 64];
  __shared__ __align__(16) bf16 sB[2][2][128 * 64];
  const int tid = threadIdx.x;
  const int w = tid >> 6, lane = tid & 63;
  const int wr = w >> 2, wc = w & 3;
  const int lr16 = lane & 15, lg = lane >> 4;
  const int NT = K >> 6;

  const int nwg = gridDim.x * gridDim.y;
  const int orig = blockIdx.y * gridDim.x + blockIdx.x;
  const int q = nwg >> 3, r = nwg & 7;
  const int xcd = orig & 7, lo = orig >> 3;
  const int swz = (xcd < r ? xcd * (q + 1) : r * (q + 1) + (xcd - r) * q) + lo;
  const int bn = (swz % gridDim.x) << 8;
  const int bm = (swz / gridDim.x) << 8;

  f32x4 acc[8][4] = {};
  bf16x8 Av[4][2], Bv0[2][2], Bv1[2][2];

  stage_chunk(A,  K, bm,       0, sA[0][0], tid, w);
  stage_chunk(Bt, K, bn,       0, sB[0][0], tid, w);
  stage_chunk(A,  K, bm + 128, 0, sA[0][1], tid, w);
  stage_chunk(Bt, K, bn + 128, 0, sB[0][1], tid, w);
  stage_chunk(A,  K, bm,       1, sA[1][0], tid, w);
  stage_chunk(Bt, K, bn,       1, sB[1][0], tid, w);

  for (int t = 0; t < NT; ++t) {
    const int b = t & 1;
    if (t < NT - 1) asm volatile("s_waitcnt vmcnt(4)" ::: "memory");
    else            asm volatile("s_waitcnt vmcnt(0)" ::: "memory");
    __builtin_amdgcn_s_barrier();

    #pragma unroll
    for (int m = 0; m < 4; ++m) {
      const int lrow = m * 32 + wr * 16 + lr16;
      Av[m][0] = lds_frag(sA[b][0], lrow, lg);
      Av[m][1] = lds_frag(sA[b][0], lrow, 4 + lg);
    }
    #pragma unroll
    for (int n = 0; n < 2; ++n) {
      const int lrow = n * 64 + wc * 16 + lr16;
      Bv0[n][0] = lds_frag(sB[b][0], lrow, lg);
      Bv0[n][1] = lds_frag(sB[b][0], lrow, 4 + lg);
    }
    if (t + 1 < NT) stage_chunk(A, K, bm + 128, t + 1, sA[b ^ 1][1], tid, w);
    __builtin_amdgcn_s_barrier();
    __builtin_amdgcn_s_setprio(1);
    #pragma unroll
    for (int m = 0; m < 4; ++m)
      #pragma unroll
      for (int n = 0; n < 2; ++n) {
        acc[m][n] = __builtin_amdgcn_mfma_f32_16x16x32_bf16(Av[m][0], Bv0[n][0], acc[m][n], 0, 0, 0);
        acc[m][n] = __builtin_amdgcn_mfma_f32_16x16x32_bf16(Av[m][1], Bv0[n][1], acc[m][n], 0, 0, 0);
      }
    __builtin_amdgcn_s_setprio(0);
    __builtin_amdgcn_s_barrier();

    #pragma unroll
    for (int n = 0; n < 2; ++n) {
      const int lrow = n * 64 + wc * 16 + lr16;
      Bv1[n][0] = lds_frag(sB[b][1], lrow, lg);
      Bv1[n][1] = lds_frag(sB[b][1], lrow, 4 + lg);
    }
    if (t + 1 < NT) stage_chunk(Bt, K, bn + 128, t + 1, sB[b ^ 1][1], tid, w);
    __builtin_amdgcn_s_barrier();
    __builtin_amdgcn_s_setprio(1);
    #pragma unroll
    for (int m = 0; m < 4; ++m)
      #pragma unroll
      for (int n = 0; n < 2; ++n) {
        acc[m][n + 2] = __builtin_amdgcn_mfma_f32_16x16x32_bf16(Av[m][0], Bv1[n][0], acc[m][n + 2], 0, 0, 0);
        acc[m][n + 2] = __builtin_amdgcn_mfma_f32_16x16x32_bf16(Av[m][1], Bv1[n][1], acc[m][n + 2], 0, 0, 0);
      }
    __builtin_amdgcn_s_setprio(0);
    __builtin_amdgcn_s_barrier();

    #pragma unroll
    for (int m = 0; m < 4; ++m) {
      const int lrow = m * 32 + wr * 16 + lr16;
      Av[m][0] = lds_frag(sA[b][1], lrow, lg);
      Av[m][1] = lds_frag(sA[b][1], lrow, 4 + lg);
    }
    if (t + 2 < NT) stage_chunk(A, K, bm, t + 2, sA[b][0], tid, w);
    __builtin_amdgcn_s_barrier();
    __builtin_amdgcn_s_setprio(1);
    #pragma unroll
    for (int m = 0; m < 4; ++m)
      #pragma unroll
      for (int n = 0; n < 2; ++n) {
        acc[m + 4][n] = __builtin_amdgcn_mfma_f32_16x16x32_bf16(Av[m][0], Bv0[n][0], acc[m + 4][n], 0, 0, 0);
        acc[m + 4][n] = __builtin_amdgcn_mfma_f32_16x16x32_bf16(Av[m][1], Bv0[n][1], acc[m + 4][n], 0, 0, 0);
      }
    __builtin_amdgcn_s_setprio(0);
    __builtin_amdgcn_s_barrier();

    if (t + 2 < NT) stage_chunk(Bt, K, bn, t + 2, sB[b][0], tid, w);
    __builtin_amdgcn_s_barrier();
    __builtin_amdgcn_s_setprio(1);
    #pragma unroll
    for (int m = 0; m < 4; ++m)
      #pragma unroll
      for (int n = 0; n < 2; ++n) {
        acc[m + 4][n + 2] = __builtin_amdgcn_mfma_f32_16x16x32_bf16(Av[m][0], Bv1[n][0], acc[m + 4][n + 2], 0, 0, 0);
        acc[m + 4][n + 2] = __builtin_amdgcn_mfma_f32_16x16x32_bf16(Av[m][1], Bv1[n][1], acc[m + 4][n + 2], 0, 0, 0);
      }
    __builtin_amdgcn_s_setprio(0);
  }

  const int g4 = (lane >> 4) << 2;
  #pragma unroll
  for (int n = 0; n < 4; ++n) {
    const int col = bn + n * 64 + wc * 16 + lr16;
    const float bvv = bias ? bias[col] : 0.f;
    #pragma unroll
    for (int m = 0; m < 8; ++m) {
      const int row = bm + m * 32 + wr * 16 + g4;
      #pragma unroll
      for (int j = 0; j < 4; ++j) {
        float v = acc[m][n][j] + bvv;
        if (RELU) v = fmaxf(v, 0.f);
        if (OUT_BF16) ((bf16*)Cv)[(size_t)(row + j) * N + col] = (bf16)v;
        else          ((float*)Cv)[(size_t)(row + j) * N + col] = v;
      }
    }
  }
}

// ============ 128x128 BK=64 GEMM: 4 waves (64x64 each), 64KB LDS, 2 blocks/CU ====
// Per K-tile: 16 ds_read (all frags) | barrier | stageA ; 16 MFMA ; stageB ; 16 MFMA.
// Stage(t+2) targets cur buffer one barrier after its last reader. vmcnt(8).
__device__ __forceinline__ void stage4(const bf16* g, size_t r32, bf16* chunk, int w) {
  load16(g,            chunk + (w << 9));
  load16(g + r32,      chunk + 2048 + (w << 9));
  load16(g + 2 * r32,  chunk + 4096 + (w << 9));
  load16(g + 3 * r32,  chunk + 6144 + (w << 9));
}

template<int OUT_BF16, int RELU>
__global__ __launch_bounds__(256, 2) void gemm128(
    const bf16* __restrict__ A, const bf16* __restrict__ Bt,
    const float* __restrict__ bias, void* __restrict__ Cv,
    int N, int K) {
  __shared__ __align__(16) bf16 sA[2][128 * 64];
  __shared__ __align__(16) bf16 sB[2][128 * 64];
  const int tid = threadIdx.x;
  const int w = tid >> 6, lane = tid & 63;
  const int wr = w >> 1, wc = w & 1;
  const int lr16 = lane & 15, lg = lane >> 4;
  const int NT = K >> 6;

  const int nwg = gridDim.x * gridDim.y;
  const int orig = blockIdx.y * gridDim.x + blockIdx.x;
  const int q = nwg >> 3, r = nwg & 7;
  const int xcd = orig & 7, lo = orig >> 3;
  const int swz = (xcd < r ? xcd * (q + 1) : r * (q + 1) + (xcd - r) * q) + lo;
  const int bn = (swz % gridDim.x) << 7;
  const int bm = (swz / gridDim.x) << 7;

  // staging base: thread's granules p = i*256 + tid -> rows rr0+32i, fixed slot
  const int rr0 = tid >> 3;                  // 0..31
  const int cb  = (tid & 7) ^ (rr0 & 7);
  const bf16* gA = A  + (size_t)(bm + rr0) * K + (cb << 3);
  const bf16* gB = Bt + (size_t)(bn + rr0) * K + (cb << 3);
  const size_t r32 = (size_t)32 * K;

  f32x4 acc[4][4] = {};
  bf16x8 Af[4][2], Bf[4][2];

  // prologue: A(0) B(0) A(1) B(1)  (16 loads)
  stage4(gA,      r32, sA[0], w);
  stage4(gB,      r32, sB[0], w);
  stage4(gA + 64, r32, sA[1], w);
  stage4(gB + 64, r32, sB[1], w);

  for (int t = 0; t < NT; ++t) {
    const int cur = t & 1;
    if (t < NT - 1) asm volatile("s_waitcnt vmcnt(8)" ::: "memory");
    else            asm volatile("s_waitcnt vmcnt(0)" ::: "memory");
    __builtin_amdgcn_s_barrier();

    #pragma unroll
    for (int m = 0; m < 4; ++m) {
      const int lrow = wr * 64 + m * 16 + lr16;
      Af[m][0] = lds_frag(sA[cur], lrow, lg);
      Af[m][1] = lds_frag(sA[cur], lrow, 4 + lg);
    }
    #pragma unroll
    for (int n = 0; n < 4; ++n) {
      const int lrow = wc * 64 + n * 16 + lr16;
      Bf[n][0] = lds_frag(sB[cur], lrow, lg);
      Bf[n][1] = lds_frag(sB[cur], lrow, 4 + lg);
    }
    __builtin_amdgcn_s_barrier();        // all reads issued; cur safe to restage

    if (t + 2 < NT) stage4(gA + (size_t)(t + 2) * 64, r32, sA[cur], w);
    __builtin_amdgcn_s_setprio(1);
    #pragma unroll
    for (int m = 0; m < 4; ++m)
      #pragma unroll
      for (int n = 0; n < 4; ++n)
        acc[m][n] = __builtin_amdgcn_mfma_f32_16x16x32_bf16(Af[m][0], Bf[n][0], acc[m][n], 0, 0, 0);
    __builtin_amdgcn_s_setprio(0);
    if (t + 2 < NT) stage4(gB + (size_t)(t + 2) * 64, r32, sB[cur], w);
    __builtin_amdgcn_s_setprio(1);
    #pragma unroll
    for (int m = 0; m < 4; ++m)
      #pragma unroll
      for (int n = 0; n < 4; ++n)
        acc[m][n] = __builtin_amdgcn_mfma_f32_16x16x32_bf16(Af[m][1], Bf[n][1], acc[m][n], 0, 0, 0);
    __builtin_amdgcn_s_setprio(0);
  }

  const int g4 = (lane >> 4) << 2;
  #pragma unroll
  for (int n = 0; n < 4; ++n) {
    const int col = bn + wc * 64 + n * 16 + lr16;
    const float bvv = bias ? bias[col] : 0.f;
    #pragma unroll
    for (int m = 0; m < 4; ++m) {
      const int row = bm + wr * 64 + m * 16 + g4;
      #pragma unroll
      for (int j = 0; j < 4; ++j) {
        float v = acc[m][n][j] + bvv;
        if (RELU) v = fmaxf(v, 0.f);
        if (OUT_BF16) ((bf16*)Cv)[(size_t)(row + j) * N + col] = (bf16)v;
        else          ((float*)Cv)[(size_t)(row + j) * N + col] = v;
      }
    }
  }
}

// ---------------- MFMA attention: one block (4 waves) per (b,h) ----------------
__global__ __launch_bounds__(256) void attn_mfma(
    const bf16* __restrict__ qkv, const int* __restrict__ mask,
    bf16* __restrict__ aout) {
  __shared__ __align__(16) bf16 sQ[ATT_R * 64];
  __shared__ __align__(16) bf16 sK[ATT_R * 64];
  __shared__ __align__(16) bf16 sVt[64 * 136];
  __shared__ __align__(16) bf16 sP[ATT_R * ATT_K];
  __shared__ int sM[ATT_R];
  const int bh = blockIdx.x, b = bh >> 3, h = bh & 7;
  const int tid = threadIdx.x, w = tid >> 6, lane = tid & 63;
  const int lr = lane & 15;
  const int lk = (lane >> 4) << 3;
  const int g  = lane >> 4;

  for (int i = tid; i < ATT_R * 64 / 8; i += 256) { ((int4*)sQ)[i] = int4{0,0,0,0}; ((int4*)sK)[i] = int4{0,0,0,0}; }
  for (int i = tid; i < 64 * 136 / 8; i += 256) ((int4*)sVt)[i] = int4{0,0,0,0};
  for (int i = tid; i < ATT_R * ATT_K / 8; i += 256) ((int4*)sP)[i] = int4{0,0,0,0};
  __syncthreads();

  const bf16* base = qkv + (size_t)(b * LL) * (3 * DD) + h * HD;
  for (int c = tid; c < LL * 8; c += 256) {
    const int l = c >> 3, u = c & 7;
    const bf16x8 qv = *(const bf16x8*)(base + (size_t)l * (3 * DD) + u * 8);
    const bf16x8 kv = *(const bf16x8*)(base + (size_t)l * (3 * DD) + DD + u * 8);
    const bf16x8 vv = *(const bf16x8*)(base + (size_t)l * (3 * DD) + 2 * DD + u * 8);
    const int qb = (l * 128 + u * 16) ^ ((l & 7) << 4);
    *(bf16x8*)((char*)sQ + qb) = qv;
    *(bf16x8*)((char*)sK + qb) = kv;
    #pragma unroll
    for (int j = 0; j < 8; ++j) sVt[(u * 8 + j) * 136 + l] = vv[j];
  }
  if (tid < ATT_R) sM[tid] = (tid < LL) ? mask[b * LL + tid] : 0;
  __syncthreads();

  #pragma unroll
  for (int fi = 0; fi < 2; ++fi) {
    const int fm = w + fi * 4;
    if (fm >= 7) continue;
    const int ar = fm * 16 + lr;
    const int abase = ar * 128;
    const int aswz = (ar & 7) << 4;
    const bf16x8 a0 = *(const bf16x8*)((char*)sQ + ((abase + lk * 2) ^ aswz));
    const bf16x8 a1 = *(const bf16x8*)((char*)sQ + ((abase + 64 + lk * 2) ^ aswz));
    f32x4 s[7];
    #pragma unroll
    for (int fn = 0; fn < 7; ++fn) {
      const int br = fn * 16 + lr;
      const int bswz = (br & 7) << 4;
      const bf16x8 b0 = *(const bf16x8*)((char*)sK + ((br * 128 + lk * 2) ^ bswz));
      const bf16x8 b1 = *(const bf16x8*)((char*)sK + ((br * 128 + 64 + lk * 2) ^ bswz));
      f32x4 acc = {};
      acc = __builtin_amdgcn_mfma_f32_16x16x32_bf16(a0, b0, acc, 0, 0, 0);
      acc = __builtin_amdgcn_mfma_f32_16x16x32_bf16(a1, b1, acc, 0, 0, 0);
      s[fn] = acc;
    }
    #pragma unroll
    for (int fn = 0; fn < 7; ++fn) {
      if (sM[fn * 16 + lr] == 0) {
        s[fn][0] = -INFINITY; s[fn][1] = -INFINITY;
        s[fn][2] = -INFINITY; s[fn][3] = -INFINITY;
      }
    }
    float sm[4];
    #pragma unroll
    for (int j = 0; j < 4; ++j) {
      float m = s[0][j];
      #pragma unroll
      for (int fn = 1; fn < 7; ++fn) m = fmaxf(m, s[fn][j]);
      #pragma unroll
      for (int off = 1; off < 16; off <<= 1) m = fmaxf(m, __shfl_xor(m, off, 64));
      float t = 0.f;
      #pragma unroll
      for (int fn = 0; fn < 7; ++fn) { const float p = __expf(s[fn][j] - m); s[fn][j] = p; t += p; }
      #pragma unroll
      for (int off = 1; off < 16; off <<= 1) t += __shfl_xor(t, off, 64);
      sm[j] = 1.f / t;
    }
    #pragma unroll
    for (int fn = 0; fn < 7; ++fn) {
      const int k = fn * 16 + lr;
      #pragma unroll
      for (int j = 0; j < 4; ++j) {
        const int rr = fm * 16 + 4 * g + j;
        const int byte = (rr * 256 + k * 2) ^ ((rr & 7) << 4);
        *(bf16*)((char*)sP + byte) = (bf16)(s[fn][j] * sm[j]);
      }
    }
  }
  __syncthreads();

  bf16x8 bV[4];
  #pragma unroll
  for (int ks = 0; ks < 4; ++ks)
    bV[ks] = *(const bf16x8*)((char*)sVt + ((w * 16 + lr) * 272 + ks * 64 + lk * 2));
  #pragma unroll
  for (int fm = 0; fm < 7; ++fm) {
    f32x4 acc = {};
    const int ar = fm * 16 + lr;
    const int aswz = (ar & 7) << 4;
    #pragma unroll
    for (int ks = 0; ks < 4; ++ks) {
      const bf16x8 aP = *(const bf16x8*)((char*)sP + ((ar * 256 + ks * 64 + lk * 2) ^ aswz));
      acc = __builtin_amdgcn_mfma_f32_16x16x32_bf16(aP, bV[ks], acc, 0, 0, 0);
    }
    const int d = h * HD + w * 16 + lr;
    #pragma unroll
    for (int j = 0; j < 4; ++j) {
      const int qr = fm * 16 + 4 * g + j;
      if (qr < LL) aout[(size_t)(b * LL + qr) * DD + d] = (bf16)acc[j];
    }
  }
}

// ---------------- residual add + LayerNorm (4 waves x 4 rows per block) ----------
template<int WRITE_F32>
__global__ __launch_bounds__(256) void ln_kernel(
    const float* __restrict__ Y, const bf16* __restrict__ RES,
    const float* __restrict__ g, const float* __restrict__ bt,
    bf16* __restrict__ XB, float* __restrict__ XF) {
  const int row = blockIdx.x * 4 + (threadIdx.x >> 6);
  const int lane = threadIdx.x & 63;
  const size_t base = (size_t)row * DD + lane * 8;
  const float4 a0 = *(const float4*)(Y + base);
  const float4 a1 = *(const float4*)(Y + base + 4);
  const bf16x8 rv = *(const bf16x8*)(RES + base);
  float z[8];
  z[0] = a0.x + (float)rv[0]; z[1] = a0.y + (float)rv[1];
  z[2] = a0.z + (float)rv[2]; z[3] = a0.w + (float)rv[3];
  z[4] = a1.x + (float)rv[4]; z[5] = a1.y + (float)rv[5];
  z[6] = a1.z + (float)rv[6]; z[7] = a1.w + (float)rv[7];
  float s = 0.f, s2 = 0.f;
  #pragma unroll
  for (int j = 0; j < 8; ++j) { s += z[j]; s2 = fmaf(z[j], z[j], s2); }
  #pragma unroll
  for (int off = 32; off > 0; off >>= 1) {
    s  += __shfl_xor(s, off, 64);
    s2 += __shfl_xor(s2, off, 64);
  }
  const float mu = s * (1.f / 512.f);
  const float var = s2 * (1.f / 512.f) - mu * mu;
  const float inv = rsqrtf(var + 1e-5f);
  const int c = lane * 8;
  const float4 g0 = *(const float4*)(g + c),  g1 = *(const float4*)(g + c + 4);
  const float4 b0 = *(const float4*)(bt + c), b1 = *(const float4*)(bt + c + 4);
  float ov[8];
  ov[0] = (z[0] - mu) * inv * g0.x + b0.x; ov[1] = (z[1] - mu) * inv * g0.y + b0.y;
  ov[2] = (z[2] - mu) * inv * g0.z + b0.z; ov[3] = (z[3] - mu) * inv * g0.w + b0.w;
  ov[4] = (z[4] - mu) * inv * g1.x + b1.x; ov[5] = (z[5] - mu) * inv * g1.y + b1.y;
  ov[6] = (z[6] - mu) * inv * g1.z + b1.z; ov[7] = (z[7] - mu) * inv * g1.w + b1.w;
  bf16x8 pk;
  #pragma unroll
  for (int j = 0; j < 8; ++j) pk[j] = (bf16)ov[j];
  *(bf16x8*)(XB + base) = pk;
  if (WRITE_F32) {
    *(float4*)(XF + base)     = make_float4(ov[0], ov[1], ov[2], ov[3]);
    *(float4*)(XF + base + 4) = make_float4(ov[4], ov[5], ov[6], ov[7]);
  }
}

extern "C" void kernel_launch(void* const* d_in, const int* in_sizes, int n_in,
                              void* d_out, int out_size, void* d_ws, size_t ws_size,
                              hipStream_t stream) {
  const float* x_in   = (const float*)d_in[0];
  const int*   mask   = (const int*)d_in[1];
  const float* qkv_w  = (const float*)d_in[2];
  const float* fc_w   = (const float*)d_in[3];
  const float* fc_b   = (const float*)d_in[4];
  const float* ln1_g  = (const float*)d_in[5];
  const float* ln1_b  = (const float*)d_in[6];
  const float* ln2_g  = (const float*)d_in[7];
  const float* ln2_b  = (const float*)d_in[8];
  const float* ffn_w1 = (const float*)d_in[9];
  const float* ffn_b1 = (const float*)d_in[10];
  const float* ffn_w2 = (const float*)d_in[11];
  const float* ffn_b2 = (const float*)d_in[12];

  char* ws = (char*)d_ws;
  size_t off = 0;
  auto alloc = [&](size_t bytes) -> void* {
    off = (off + 255) & ~(size_t)255;
    void* p = ws + off;
    off += bytes;
    return p;
  };
  bf16*  XB   = (bf16*) alloc((size_t)MM * DD * 2);
  bf16*  BIGB = (bf16*) alloc((size_t)MM * FF * 2);
  float* PE   = (float*)alloc((size_t)LL * DD * 4);
  bf16*  WQKV = (bf16*) alloc((size_t)NLAYERS * DD * 3 * DD * 2);
  bf16*  WFC  = (bf16*) alloc((size_t)NLAYERS * DD * DD * 2);
  bf16*  W1T  = (bf16*) alloc((size_t)NLAYERS * DD * FF * 2);
  bf16*  W2T  = (bf16*) alloc((size_t)NLAYERS * FF * DD * 2);
  bf16*  AOUT = BIGB + (size_t)MM * (3 * DD);
  float* Y    = (float*)d_out;
  (void)ws_size; (void)in_sizes; (void)n_in; (void)out_size;

  pe_kernel<<<200, 256, 0, stream>>>(PE);
  transpose_cast<<<dim3(48, 16, NLAYERS), dim3(32, 8), 0, stream>>>(qkv_w,  WQKV, 512, 1536);
  transpose_cast<<<dim3(16, 16, NLAYERS), dim3(32, 8), 0, stream>>>(fc_w,   WFC,  512, 512);
  transpose_cast<<<dim3(64, 16, NLAYERS), dim3(32, 8), 0, stream>>>(ffn_w1, W1T,  512, 2048);
  transpose_cast<<<dim3(16, 64, NLAYERS), dim3(32, 8), 0, stream>>>(ffn_w2, W2T,  2048, 512);
  x0_kernel<<<12800, 256, 0, stream>>>(x_in, PE, XB);

  for (int i = 0; i < NLAYERS; ++i) {
    // qkv = x @ qkv_w -> bf16 [M,1536]
    gemm256<1, 0><<<dim3(6, 100), 512, 0, stream>>>(
        XB, WQKV + (size_t)i * DD * 3 * DD, nullptr, BIGB, 3 * DD, DD);
    attn_mfma<<<BB * NH, 256, 0, stream>>>(BIGB, mask, AOUT);
    // attn proj + bias -> fp32 Y (gemm128: 800 blocks, 2 blocks/CU)
    gemm128<0, 0><<<dim3(4, 200), 256, 0, stream>>>(
        AOUT, WFC + (size_t)i * DD * DD, fc_b + i * DD, Y, DD, DD);
    // x = LN(Y + x)
    ln_kernel<0><<<MM / 4, 256, 0, stream>>>(Y, XB, ln1_g + i * DD, ln1_b + i * DD, XB, nullptr);
    // h = relu(x @ w1 + b1) -> bf16 [M,2048]
    gemm256<1, 1><<<dim3(8, 100), 512, 0, stream>>>(
        XB, W1T + (size_t)i * DD * FF, ffn_b1 + i * FF, BIGB, FF, DD);
    // y = h @ w2 + b2 -> fp32 Y (gemm128)
    gemm128<0, 0><<<dim3(4, 200), 256, 0, stream>>>(
        BIGB, W2T + (size_t)i * FF * DD, ffn_b2 + i * DD, Y, DD, FF);
    // x = LN(Y + x); final layer also writes fp32 d_out (in place on Y rows)
    if (i == NLAYERS - 1)
      ln_kernel<1><<<MM / 4, 256, 0, stream>>>(Y, XB, ln2_g + i * DD, ln2_b + i * DD,
                                               XB, (float*)d_out);
    else
      ln_kernel<0><<<MM / 4, 256, 0, stream>>>(Y, XB, ln2_g + i * DD, ln2_b + i * DD, XB, nullptr);
  }
}

// Round 11
// 1125.846 us; speedup vs baseline: 1.5291x; 1.0651x over previous
//
#include <hip/hip_runtime.h>
#include <cstdint>
#include <cmath>

// Transformer encoder: B=256, L=100, D=512, F=2048, NL=4, H=8, hd=64.
// Round-11: ALL GEMMs on gemm128 BK=64 (16-MFMA phases, 64KB LDS, 2 blocks/CU)
// — round-10 A/B showed it beats gemm256 per-FLOP (790 vs 625 TF).

#define NLAYERS 4
#define BB 256
#define LL 100
#define DD 512
#define FF 2048
#define NH 8
#define HD 64
#define MM (BB*LL)   // 25600 rows
#define ATT_R 112
#define ATT_K 128

typedef __bf16 bf16;
typedef bf16 bf16x8 __attribute__((ext_vector_type(8)));
typedef bf16 bf16x4 __attribute__((ext_vector_type(4)));
typedef float f32x4 __attribute__((ext_vector_type(4)));

__device__ __forceinline__ void load16(const void* g, void* l) {
  __builtin_amdgcn_global_load_lds(
      (const __attribute__((address_space(1))) void*)g,
      (__attribute__((address_space(3))) void*)l, 16, 0, 0);
}

// ---------------- positional encoding table [L][D] ----------------
__global__ void pe_kernel(float* __restrict__ pe) {
  const int idx = blockIdx.x * 256 + threadIdx.x;
  if (idx >= LL * DD) return;
  const int l = idx >> 9, d = idx & 511;
  const int i = d >> 1;
  const float div = expf((float)(2 * i) * (-9.210340371976184f / 512.f));
  const float ang = (float)l * div;
  pe[idx] = (d & 1) ? cosf(ang) : sinf(ang);
}

// ---------------- xb = bf16(2*x + pe) ----------------
__global__ __launch_bounds__(256) void x0_kernel(
    const float* __restrict__ xin, const float* __restrict__ pe,
    bf16* __restrict__ XB) {
  const size_t f = (size_t)blockIdx.x * 256 + threadIdx.x;
  const size_t e = f << 2;
  const int col  = (int)(e & 511);
  const int prow = (int)((e >> 9) % LL);
  const float4 xv = *(const float4*)(xin + e);
  const float4 pv = *(const float4*)(pe + (size_t)prow * DD + col);
  bf16x4 pk;
  pk[0] = (bf16)(2.f * xv.x + pv.x);
  pk[1] = (bf16)(2.f * xv.y + pv.y);
  pk[2] = (bf16)(2.f * xv.z + pv.z);
  pk[3] = (bf16)(2.f * xv.w + pv.w);
  *(bf16x4*)(XB + e) = pk;
}

// ---------------- weight cast + transpose: [K][N] f32 -> [N][K] bf16 ----------------
__global__ void transpose_cast(const float* __restrict__ src, bf16* __restrict__ dst,
                               int K, int N) {
  __shared__ float tile[32][33];
  const int z = blockIdx.z;
  src += (size_t)z * K * N;
  dst += (size_t)z * K * N;
  const int k0 = blockIdx.y * 32, n0 = blockIdx.x * 32;
  const int tx = threadIdx.x, ty = threadIdx.y;
  #pragma unroll
  for (int i = 0; i < 32; i += 8)
    tile[ty + i][tx] = src[(size_t)(k0 + ty + i) * N + n0 + tx];
  __syncthreads();
  #pragma unroll
  for (int i = 0; i < 32; i += 8)
    dst[(size_t)(n0 + ty + i) * K + k0 + tx] = (bf16)tile[tx][ty + i];
}

// ============ shared GEMM helpers (row*128B, 8 slots, XOR r&7 swizzle) ============
__device__ __forceinline__ bf16x8 lds_frag(const bf16* chunk, int lrow, int cb) {
  return *(const bf16x8*)(chunk + (lrow << 6) + ((cb ^ (lrow & 7)) << 3));
}

// ============ 128x128 BK=64 GEMM: 4 waves (64x64 each), 64KB LDS, 2 blocks/CU ====
// Per K-tile: 16 ds_read (all frags) | barrier | stageA ; 16 MFMA ; stageB ; 16 MFMA.
// Stage(t+2) targets cur buffer one barrier after its reads issue. vmcnt(8).
__device__ __forceinline__ void stage4(const bf16* g, size_t r32, bf16* chunk, int w) {
  load16(g,            chunk + (w << 9));
  load16(g + r32,      chunk + 2048 + (w << 9));
  load16(g + 2 * r32,  chunk + 4096 + (w << 9));
  load16(g + 3 * r32,  chunk + 6144 + (w << 9));
}

template<int OUT_BF16, int RELU>
__global__ __launch_bounds__(256, 2) void gemm128(
    const bf16* __restrict__ A, const bf16* __restrict__ Bt,
    const float* __restrict__ bias, void* __restrict__ Cv,
    int N, int K) {
  __shared__ __align__(16) bf16 sA[2][128 * 64];
  __shared__ __align__(16) bf16 sB[2][128 * 64];
  const int tid = threadIdx.x;
  const int w = tid >> 6, lane = tid & 63;
  const int wr = w >> 1, wc = w & 1;
  const int lr16 = lane & 15, lg = lane >> 4;
  const int NT = K >> 6;

  const int nwg = gridDim.x * gridDim.y;
  const int orig = blockIdx.y * gridDim.x + blockIdx.x;
  const int q = nwg >> 3, r = nwg & 7;
  const int xcd = orig & 7, lo = orig >> 3;
  const int swz = (xcd < r ? xcd * (q + 1) : r * (q + 1) + (xcd - r) * q) + lo;
  const int bn = (swz % gridDim.x) << 7;
  const int bm = (swz / gridDim.x) << 7;

  // staging base: thread's granules p = i*256 + tid -> rows rr0+32i, fixed slot
  const int rr0 = tid >> 3;                  // 0..31
  const int cb  = (tid & 7) ^ (rr0 & 7);
  const bf16* gA = A  + (size_t)(bm + rr0) * K + (cb << 3);
  const bf16* gB = Bt + (size_t)(bn + rr0) * K + (cb << 3);
  const size_t r32 = (size_t)32 * K;

  f32x4 acc[4][4] = {};
  bf16x8 Af[4][2], Bf[4][2];

  // prologue: A(0) B(0) A(1) B(1)  (16 loads)
  stage4(gA,      r32, sA[0], w);
  stage4(gB,      r32, sB[0], w);
  stage4(gA + 64, r32, sA[1], w);
  stage4(gB + 64, r32, sB[1], w);

  for (int t = 0; t < NT; ++t) {
    const int cur = t & 1;
    if (t < NT - 1) asm volatile("s_waitcnt vmcnt(8)" ::: "memory");
    else            asm volatile("s_waitcnt vmcnt(0)" ::: "memory");
    __builtin_amdgcn_s_barrier();

    #pragma unroll
    for (int m = 0; m < 4; ++m) {
      const int lrow = wr * 64 + m * 16 + lr16;
      Af[m][0] = lds_frag(sA[cur], lrow, lg);
      Af[m][1] = lds_frag(sA[cur], lrow, 4 + lg);
    }
    #pragma unroll
    for (int n = 0; n < 4; ++n) {
      const int lrow = wc * 64 + n * 16 + lr16;
      Bf[n][0] = lds_frag(sB[cur], lrow, lg);
      Bf[n][1] = lds_frag(sB[cur], lrow, 4 + lg);
    }
    __builtin_amdgcn_s_barrier();        // all reads issued; cur safe to restage

    if (t + 2 < NT) stage4(gA + (size_t)(t + 2) * 64, r32, sA[cur], w);
    __builtin_amdgcn_s_setprio(1);
    #pragma unroll
    for (int m = 0; m < 4; ++m)
      #pragma unroll
      for (int n = 0; n < 4; ++n)
        acc[m][n] = __builtin_amdgcn_mfma_f32_16x16x32_bf16(Af[m][0], Bf[n][0], acc[m][n], 0, 0, 0);
    __builtin_amdgcn_s_setprio(0);
    if (t + 2 < NT) stage4(gB + (size_t)(t + 2) * 64, r32, sB[cur], w);
    __builtin_amdgcn_s_setprio(1);
    #pragma unroll
    for (int m = 0; m < 4; ++m)
      #pragma unroll
      for (int n = 0; n < 4; ++n)
        acc[m][n] = __builtin_amdgcn_mfma_f32_16x16x32_bf16(Af[m][1], Bf[n][1], acc[m][n], 0, 0, 0);
    __builtin_amdgcn_s_setprio(0);
  }

  const int g4 = (lane >> 4) << 2;
  #pragma unroll
  for (int n = 0; n < 4; ++n) {
    const int col = bn + wc * 64 + n * 16 + lr16;
    const float bvv = bias ? bias[col] : 0.f;
    #pragma unroll
    for (int m = 0; m < 4; ++m) {
      const int row = bm + wr * 64 + m * 16 + g4;
      #pragma unroll
      for (int j = 0; j < 4; ++j) {
        float v = acc[m][n][j] + bvv;
        if (RELU) v = fmaxf(v, 0.f);
        if (OUT_BF16) ((bf16*)Cv)[(size_t)(row + j) * N + col] = (bf16)v;
        else          ((float*)Cv)[(size_t)(row + j) * N + col] = v;
      }
    }
  }
}

// ---------------- MFMA attention: one block (4 waves) per (b,h) ----------------
__global__ __launch_bounds__(256) void attn_mfma(
    const bf16* __restrict__ qkv, const int* __restrict__ mask,
    bf16* __restrict__ aout) {
  __shared__ __align__(16) bf16 sQ[ATT_R * 64];
  __shared__ __align__(16) bf16 sK[ATT_R * 64];
  __shared__ __align__(16) bf16 sVt[64 * 136];
  __shared__ __align__(16) bf16 sP[ATT_R * ATT_K];
  __shared__ int sM[ATT_R];
  const int bh = blockIdx.x, b = bh >> 3, h = bh & 7;
  const int tid = threadIdx.x, w = tid >> 6, lane = tid & 63;
  const int lr = lane & 15;
  const int lk = (lane >> 4) << 3;
  const int g  = lane >> 4;

  for (int i = tid; i < ATT_R * 64 / 8; i += 256) { ((int4*)sQ)[i] = int4{0,0,0,0}; ((int4*)sK)[i] = int4{0,0,0,0}; }
  for (int i = tid; i < 64 * 136 / 8; i += 256) ((int4*)sVt)[i] = int4{0,0,0,0};
  for (int i = tid; i < ATT_R * ATT_K / 8; i += 256) ((int4*)sP)[i] = int4{0,0,0,0};
  __syncthreads();

  const bf16* base = qkv + (size_t)(b * LL) * (3 * DD) + h * HD;
  for (int c = tid; c < LL * 8; c += 256) {
    const int l = c >> 3, u = c & 7;
    const bf16x8 qv = *(const bf16x8*)(base + (size_t)l * (3 * DD) + u * 8);
    const bf16x8 kv = *(const bf16x8*)(base + (size_t)l * (3 * DD) + DD + u * 8);
    const bf16x8 vv = *(const bf16x8*)(base + (size_t)l * (3 * DD) + 2 * DD + u * 8);
    const int qb = (l * 128 + u * 16) ^ ((l & 7) << 4);
    *(bf16x8*)((char*)sQ + qb) = qv;
    *(bf16x8*)((char*)sK + qb) = kv;
    #pragma unroll
    for (int j = 0; j < 8; ++j) sVt[(u * 8 + j) * 136 + l] = vv[j];
  }
  if (tid < ATT_R) sM[tid] = (tid < LL) ? mask[b * LL + tid] : 0;
  __syncthreads();

  #pragma unroll
  for (int fi = 0; fi < 2; ++fi) {
    const int fm = w + fi * 4;
    if (fm >= 7) continue;
    const int ar = fm * 16 + lr;
    const int abase = ar * 128;
    const int aswz = (ar & 7) << 4;
    const bf16x8 a0 = *(const bf16x8*)((char*)sQ + ((abase + lk * 2) ^ aswz));
    const bf16x8 a1 = *(const bf16x8*)((char*)sQ + ((abase + 64 + lk * 2) ^ aswz));
    f32x4 s[7];
    #pragma unroll
    for (int fn = 0; fn < 7; ++fn) {
      const int br = fn * 16 + lr;
      const int bswz = (br & 7) << 4;
      const bf16x8 b0 = *(const bf16x8*)((char*)sK + ((br * 128 + lk * 2) ^ bswz));
      const bf16x8 b1 = *(const bf16x8*)((char*)sK + ((br * 128 + 64 + lk * 2) ^ bswz));
      f32x4 acc = {};
      acc = __builtin_amdgcn_mfma_f32_16x16x32_bf16(a0, b0, acc, 0, 0, 0);
      acc = __builtin_amdgcn_mfma_f32_16x16x32_bf16(a1, b1, acc, 0, 0, 0);
      s[fn] = acc;
    }
    #pragma unroll
    for (int fn = 0; fn < 7; ++fn) {
      if (sM[fn * 16 + lr] == 0) {
        s[fn][0] = -INFINITY; s[fn][1] = -INFINITY;
        s[fn][2] = -INFINITY; s[fn][3] = -INFINITY;
      }
    }
    float sm[4];
    #pragma unroll
    for (int j = 0; j < 4; ++j) {
      float m = s[0][j];
      #pragma unroll
      for (int fn = 1; fn < 7; ++fn) m = fmaxf(m, s[fn][j]);
      #pragma unroll
      for (int off = 1; off < 16; off <<= 1) m = fmaxf(m, __shfl_xor(m, off, 64));
      float t = 0.f;
      #pragma unroll
      for (int fn = 0; fn < 7; ++fn) { const float p = __expf(s[fn][j] - m); s[fn][j] = p; t += p; }
      #pragma unroll
      for (int off = 1; off < 16; off <<= 1) t += __shfl_xor(t, off, 64);
      sm[j] = 1.f / t;
    }
    #pragma unroll
    for (int fn = 0; fn < 7; ++fn) {
      const int k = fn * 16 + lr;
      #pragma unroll
      for (int j = 0; j < 4; ++j) {
        const int rr = fm * 16 + 4 * g + j;
        const int byte = (rr * 256 + k * 2) ^ ((rr & 7) << 4);
        *(bf16*)((char*)sP + byte) = (bf16)(s[fn][j] * sm[j]);
      }
    }
  }
  __syncthreads();

  bf16x8 bV[4];
  #pragma unroll
  for (int ks = 0; ks < 4; ++ks)
    bV[ks] = *(const bf16x8*)((char*)sVt + ((w * 16 + lr) * 272 + ks * 64 + lk * 2));
  #pragma unroll
  for (int fm = 0; fm < 7; ++fm) {
    f32x4 acc = {};
    const int ar = fm * 16 + lr;
    const int aswz = (ar & 7) << 4;
    #pragma unroll
    for (int ks = 0; ks < 4; ++ks) {
      const bf16x8 aP = *(const bf16x8*)((char*)sP + ((ar * 256 + ks * 64 + lk * 2) ^ aswz));
      acc = __builtin_amdgcn_mfma_f32_16x16x32_bf16(aP, bV[ks], acc, 0, 0, 0);
    }
    const int d = h * HD + w * 16 + lr;
    #pragma unroll
    for (int j = 0; j < 4; ++j) {
      const int qr = fm * 16 + 4 * g + j;
      if (qr < LL) aout[(size_t)(b * LL + qr) * DD + d] = (bf16)acc[j];
    }
  }
}

// ---------------- residual add + LayerNorm (4 waves x 4 rows per block) ----------
template<int WRITE_F32>
__global__ __launch_bounds__(256) void ln_kernel(
    const float* __restrict__ Y, const bf16* __restrict__ RES,
    const float* __restrict__ g, const float* __restrict__ bt,
    bf16* __restrict__ XB, float* __restrict__ XF) {
  const int row = blockIdx.x * 4 + (threadIdx.x >> 6);
  const int lane = threadIdx.x & 63;
  const size_t base = (size_t)row * DD + lane * 8;
  const float4 a0 = *(const float4*)(Y + base);
  const float4 a1 = *(const float4*)(Y + base + 4);
  const bf16x8 rv = *(const bf16x8*)(RES + base);
  float z[8];
  z[0] = a0.x + (float)rv[0]; z[1] = a0.y + (float)rv[1];
  z[2] = a0.z + (float)rv[2]; z[3] = a0.w + (float)rv[3];
  z[4] = a1.x + (float)rv[4]; z[5] = a1.y + (float)rv[5];
  z[6] = a1.z + (float)rv[6]; z[7] = a1.w + (float)rv[7];
  float s = 0.f, s2 = 0.f;
  #pragma unroll
  for (int j = 0; j < 8; ++j) { s += z[j]; s2 = fmaf(z[j], z[j], s2); }
  #pragma unroll
  for (int off = 32; off > 0; off >>= 1) {
    s  += __shfl_xor(s, off, 64);
    s2 += __shfl_xor(s2, off, 64);
  }
  const float mu = s * (1.f / 512.f);
  const float var = s2 * (1.f / 512.f) - mu * mu;
  const float inv = rsqrtf(var + 1e-5f);
  const int c = lane * 8;
  const float4 g0 = *(const float4*)(g + c),  g1 = *(const float4*)(g + c + 4);
  const float4 b0 = *(const float4*)(bt + c), b1 = *(const float4*)(bt + c + 4);
  float ov[8];
  ov[0] = (z[0] - mu) * inv * g0.x + b0.x; ov[1] = (z[1] - mu) * inv * g0.y + b0.y;
  ov[2] = (z[2] - mu) * inv * g0.z + b0.z; ov[3] = (z[3] - mu) * inv * g0.w + b0.w;
  ov[4] = (z[4] - mu) * inv * g1.x + b1.x; ov[5] = (z[5] - mu) * inv * g1.y + b1.y;
  ov[6] = (z[6] - mu) * inv * g1.z + b1.z; ov[7] = (z[7] - mu) * inv * g1.w + b1.w;
  bf16x8 pk;
  #pragma unroll
  for (int j = 0; j < 8; ++j) pk[j] = (bf16)ov[j];
  *(bf16x8*)(XB + base) = pk;
  if (WRITE_F32) {
    *(float4*)(XF + base)     = make_float4(ov[0], ov[1], ov[2], ov[3]);
    *(float4*)(XF + base + 4) = make_float4(ov[4], ov[5], ov[6], ov[7]);
  }
}

extern "C" void kernel_launch(void* const* d_in, const int* in_sizes, int n_in,
                              void* d_out, int out_size, void* d_ws, size_t ws_size,
                              hipStream_t stream) {
  const float* x_in   = (const float*)d_in[0];
  const int*   mask   = (const int*)d_in[1];
  const float* qkv_w  = (const float*)d_in[2];
  const float* fc_w   = (const float*)d_in[3];
  const float* fc_b   = (const float*)d_in[4];
  const float* ln1_g  = (const float*)d_in[5];
  const float* ln1_b  = (const float*)d_in[6];
  const float* ln2_g  = (const float*)d_in[7];
  const float* ln2_b  = (const float*)d_in[8];
  const float* ffn_w1 = (const float*)d_in[9];
  const float* ffn_b1 = (const float*)d_in[10];
  const float* ffn_w2 = (const float*)d_in[11];
  const float* ffn_b2 = (const float*)d_in[12];

  char* ws = (char*)d_ws;
  size_t off = 0;
  auto alloc = [&](size_t bytes) -> void* {
    off = (off + 255) & ~(size_t)255;
    void* p = ws + off;
    off += bytes;
    return p;
  };
  bf16*  XB   = (bf16*) alloc((size_t)MM * DD * 2);
  bf16*  BIGB = (bf16*) alloc((size_t)MM * FF * 2);
  float* PE   = (float*)alloc((size_t)LL * DD * 4);
  bf16*  WQKV = (bf16*) alloc((size_t)NLAYERS * DD * 3 * DD * 2);
  bf16*  WFC  = (bf16*) alloc((size_t)NLAYERS * DD * DD * 2);
  bf16*  W1T  = (bf16*) alloc((size_t)NLAYERS * DD * FF * 2);
  bf16*  W2T  = (bf16*) alloc((size_t)NLAYERS * FF * DD * 2);
  bf16*  AOUT = BIGB + (size_t)MM * (3 * DD);
  float* Y    = (float*)d_out;
  (void)ws_size; (void)in_sizes; (void)n_in; (void)out_size;

  pe_kernel<<<200, 256, 0, stream>>>(PE);
  transpose_cast<<<dim3(48, 16, NLAYERS), dim3(32, 8), 0, stream>>>(qkv_w,  WQKV, 512, 1536);
  transpose_cast<<<dim3(16, 16, NLAYERS), dim3(32, 8), 0, stream>>>(fc_w,   WFC,  512, 512);
  transpose_cast<<<dim3(64, 16, NLAYERS), dim3(32, 8), 0, stream>>>(ffn_w1, W1T,  512, 2048);
  transpose_cast<<<dim3(16, 64, NLAYERS), dim3(32, 8), 0, stream>>>(ffn_w2, W2T,  2048, 512);
  x0_kernel<<<12800, 256, 0, stream>>>(x_in, PE, XB);

  for (int i = 0; i < NLAYERS; ++i) {
    // qkv = x @ qkv_w -> bf16 [M,1536]   (gemm128, 2400 blocks)
    gemm128<1, 0><<<dim3(12, 200), 256, 0, stream>>>(
        XB, WQKV + (size_t)i * DD * 3 * DD, nullptr, BIGB, 3 * DD, DD);
    attn_mfma<<<BB * NH, 256, 0, stream>>>(BIGB, mask, AOUT);
    // attn proj + bias -> fp32 Y (gemm128, 800 blocks)
    gemm128<0, 0><<<dim3(4, 200), 256, 0, stream>>>(
        AOUT, WFC + (size_t)i * DD * DD, fc_b + i * DD, Y, DD, DD);
    // x = LN(Y + x)
    ln_kernel<0><<<MM / 4, 256, 0, stream>>>(Y, XB, ln1_g + i * DD, ln1_b + i * DD, XB, nullptr);
    // h = relu(x @ w1 + b1) -> bf16 [M,2048]  (gemm128, 3200 blocks)
    gemm128<1, 1><<<dim3(16, 200), 256, 0, stream>>>(
        XB, W1T + (size_t)i * DD * FF, ffn_b1 + i * FF, BIGB, FF, DD);
    // y = h @ w2 + b2 -> fp32 Y (gemm128)
    gemm128<0, 0><<<dim3(4, 200), 256, 0, stream>>>(
        BIGB, W2T + (size_t)i * FF * DD, ffn_b2 + i * DD, Y, DD, FF);
    // x = LN(Y + x); final layer also writes fp32 d_out (in place on Y rows)
    if (i == NLAYERS - 1)
      ln_kernel<1><<<MM / 4, 256, 0, stream>>>(Y, XB, ln2_g + i * DD, ln2_b + i * DD,
                                               XB, (float*)d_out);
    else
      ln_kernel<0><<<MM / 4, 256, 0, stream>>>(Y, XB, ln2_g + i * DD, ln2_b + i * DD, XB, nullptr);
  }
}